// Round 1
// baseline (349.095 us; speedup 1.0000x reference)
//
#include <hip/hip_runtime.h>
#include <cstddef>

// MultiHeadAttentionLayer: B=2, S=2048, D=1024, H=16, DEPTH=64
// Pipeline (all bf16 MFMA, fp32 softmax/accum):
//   wt_transpose: Wq,Wv,Wo (f32 KxN) -> bf16 W^T (NxK) in ws
//   gemm_bt<true,false>: Qp = bf16(q @ Wq + bq), Kp = bf16(k @ Wq + bq)  [ref uses wQuery for K],
//                        Vp = bf16(v @ Wv + bv)
//   attn: flash-style online softmax per (b,h,64-row q-tile) -> AO (bf16)
//   gemm_bt<false,true>: out = AO @ Wo + bo (f32)
// ws usage: 3*1M u16 (weights) + 4*4M u16 (Qp,Kp,Vp,AO) = 38 MB.

namespace {

constexpr int Ss = 2048;
constexpr int Dd = 1024;
constexpr int Hh = 16;

typedef unsigned short u16;
typedef __attribute__((ext_vector_type(8))) __bf16 bf16x8;
typedef __attribute__((ext_vector_type(4))) float f32x4;
typedef __attribute__((ext_vector_type(8))) unsigned short us8;

__device__ __forceinline__ u16 f2bf(float f) {
  unsigned int u = __float_as_uint(f);
  return (u16)((u + 0x7fffu + ((u >> 16) & 1u)) >> 16);  // RNE
}

__device__ __forceinline__ void gload_lds16(const void* g, void* l) {
  __builtin_amdgcn_global_load_lds(
      (__attribute__((address_space(1))) void*)g,
      (__attribute__((address_space(3))) void*)l, 16, 0, 0);
}

__device__ __forceinline__ f32x4 mfma16(bf16x8 a, bf16x8 b, f32x4 c) {
  return __builtin_amdgcn_mfma_f32_16x16x32_bf16(a, b, c, 0, 0, 0);
}

// ---------------------------------------------------------------- transpose
// W (f32, K-major 1024x1024) -> WT (bf16, N-major 1024x1024), 3 weights via z.
__global__ __launch_bounds__(256) void wt_transpose(const float* __restrict__ W0,
                                                    const float* __restrict__ W1,
                                                    const float* __restrict__ W2,
                                                    u16* __restrict__ wsbase) {
  const float* W = (blockIdx.z == 0) ? W0 : (blockIdx.z == 1) ? W1 : W2;
  u16* WT = wsbase + (size_t)blockIdx.z * (1024 * 1024);
  __shared__ float tile[32][33];
  const int tx = threadIdx.x & 31;
  const int ty = threadIdx.x >> 5;  // 0..7
  const int n0 = blockIdx.x * 32;
  const int k0 = blockIdx.y * 32;
#pragma unroll
  for (int i = 0; i < 4; ++i)
    tile[ty + i * 8][tx] = W[(size_t)(k0 + ty + i * 8) * 1024 + n0 + tx];
  __syncthreads();
#pragma unroll
  for (int i = 0; i < 4; ++i)
    WT[(size_t)(n0 + ty + i * 8) * 1024 + k0 + tx] = f2bf(tile[tx][ty + i * 8]);
}

// ---------------------------------------------------------------- GEMM (B^T)
// C[M,N] = A[M,K] @ BT[N,K]^T + bias[N].  128x128 tile, BK=64, 4 waves.
// A_F32: A is f32, reg-staged+converted; else bf16 via global_load_lds.
// C_F32: C stored f32 (d_out); else bf16 (ws).
template <bool A_F32, bool C_F32>
__global__ __launch_bounds__(256) void gemm_bt(const void* __restrict__ Ap,
                                               const u16* __restrict__ Bt,
                                               const float* __restrict__ bias,
                                               void* __restrict__ Cp,
                                               int M, int N, int K) {
  __shared__ u16 As[128 * 64];
  __shared__ u16 Bs[128 * 64];
  const int tid = threadIdx.x;
  const int wid = tid >> 6;
  const int lane = tid & 63;
  const int g = lane >> 4;
  const int lr = lane & 15;
  const int n0 = blockIdx.x * 128;
  const int m0 = blockIdx.y * 128;
  const int wr = wid >> 1, wc = wid & 1;  // wave -> 64x64 quadrant

  const f32x4 zero = {0.f, 0.f, 0.f, 0.f};
  f32x4 acc[4][4];
#pragma unroll
  for (int m = 0; m < 4; ++m)
#pragma unroll
    for (int n = 0; n < 4; ++n) acc[m][n] = zero;

  for (int k0 = 0; k0 < K; k0 += 64) {
    if constexpr (A_F32) {
      const float* A = (const float*)Ap;
#pragma unroll
      for (int i = 0; i < 8; ++i) {
        int e = i * 256 + tid;          // 2048 float4-chunks of the 128x64 tile
        int row = e >> 4;
        int c4 = (e & 15) << 2;
        const float4 v = *(const float4*)(&A[(size_t)(m0 + row) * K + k0 + c4]);
        ushort4 o4 = make_ushort4(f2bf(v.x), f2bf(v.y), f2bf(v.z), f2bf(v.w));
        *(ushort4*)(&As[row * 64 + c4]) = o4;
      }
    } else {
      const u16* A = (const u16*)Ap;
#pragma unroll
      for (int j = 0; j < 4; ++j) {
        int rb = (wid * 4 + j) * 8;  // 8 rows per instruction
        gload_lds16(&A[(size_t)(m0 + rb + (lane >> 3)) * K + k0 + (lane & 7) * 8],
                    &As[rb * 64]);
      }
    }
#pragma unroll
    for (int j = 0; j < 4; ++j) {
      int rb = (wid * 4 + j) * 8;
      gload_lds16(&Bt[(size_t)(n0 + rb + (lane >> 3)) * K + k0 + (lane & 7) * 8],
                  &Bs[rb * 64]);
    }
    __syncthreads();
#pragma unroll
    for (int kk = 0; kk < 2; ++kk) {
      bf16x8 a[4], b[4];
#pragma unroll
      for (int m = 0; m < 4; ++m)
        a[m] = *(const bf16x8*)(&As[(wr * 64 + m * 16 + lr) * 64 + kk * 32 + g * 8]);
#pragma unroll
      for (int n = 0; n < 4; ++n)
        b[n] = *(const bf16x8*)(&Bs[(wc * 64 + n * 16 + lr) * 64 + kk * 32 + g * 8]);
#pragma unroll
      for (int m = 0; m < 4; ++m)
#pragma unroll
        for (int n = 0; n < 4; ++n) acc[m][n] = mfma16(a[m], b[n], acc[m][n]);
    }
    __syncthreads();
  }
  // epilogue: C/D layout col=lane&15, row=(lane>>4)*4+reg  [m89-verified]
#pragma unroll
  for (int n = 0; n < 4; ++n) {
    const int col = n0 + wc * 64 + n * 16 + lr;
    const float bv = bias[col];
#pragma unroll
    for (int m = 0; m < 4; ++m) {
      const int rowb = m0 + wr * 64 + m * 16 + g * 4;
#pragma unroll
      for (int r = 0; r < 4; ++r) {
        float val = acc[m][n][r] + bv;
        if constexpr (C_F32)
          ((float*)Cp)[(size_t)(rowb + r) * N + col] = val;
        else
          ((u16*)Cp)[(size_t)(rowb + r) * N + col] = f2bf(val);
      }
    }
  }
}

// ---------------------------------------------------------------- attention
// grid: (S/64, B*H). Block = 4 waves; wave w owns q-rows [q0+16w, q0+16w+16).
// KV tiles of 64 keys; K staged via global_load_lds, V staged transposed.
__global__ __launch_bounds__(256) void attn(const u16* __restrict__ Qp,
                                            const u16* __restrict__ Kp,
                                            const u16* __restrict__ Vp,
                                            const float* __restrict__ mask,
                                            u16* __restrict__ Op) {
  __shared__ u16 Ks[64 * 64];      // Ks[key][d]
  __shared__ u16 Vt[64 * 64];      // Vt[d][key]  (transposed)
  __shared__ u16 Ps[4][16 * 64];   // per-wave P tile [row][key]
  __shared__ float ms[64];         // mask * -1e9 for this key tile
  const int tid = threadIdx.x;
  const int wid = tid >> 6;
  const int lane = tid & 63;
  const int g = lane >> 4;
  const int lr = lane & 15;
  const int q0 = blockIdx.x * 64;
  const int bh = blockIdx.y;
  const int b = bh >> 4;
  const int h = bh & 15;
  const size_t base = ((size_t)b * Ss) * Dd + (size_t)h * 64;

  // Q fragments (A operand): lane row = lr, k = kk*32 + g*8 .. +8
  bf16x8 qf[2];
  {
    const int row = q0 + wid * 16 + lr;
#pragma unroll
    for (int kk = 0; kk < 2; ++kk)
      qf[kk] = *(const bf16x8*)(&Qp[base + (size_t)row * Dd + kk * 32 + g * 8]);
  }

  const f32x4 zero = {0.f, 0.f, 0.f, 0.f};
  f32x4 o[4];
#pragma unroll
  for (int i = 0; i < 4; ++i) o[i] = zero;
  float mrun[4], lrun[4];
#pragma unroll
  for (int r = 0; r < 4; ++r) {
    mrun[r] = -1e30f;
    lrun[r] = 0.f;
  }

  for (int t = 0; t < Ss / 64; ++t) {
    const int key0 = t * 64;
    // stage K tile (8 rows per gload, 2 per wave)
#pragma unroll
    for (int j = 0; j < 2; ++j) {
      int rb = (wid * 2 + j) * 8;
      gload_lds16(&Kp[base + (size_t)(key0 + rb + (lane >> 3)) * Dd + (lane & 7) * 8],
                  &Ks[rb * 64]);
    }
    // stage V transposed (reg-staged)
#pragma unroll
    for (int i = 0; i < 2; ++i) {
      int idx = i * 256 + tid;
      int key = idx >> 3;
      int dc = (idx & 7) * 8;
      us8 v8 = *(const us8*)(&Vp[base + (size_t)(key0 + key) * Dd + dc]);
#pragma unroll
      for (int j = 0; j < 8; ++j) Vt[(dc + j) * 64 + key] = v8[j];
    }
    if (tid < 64) ms[tid] = mask[(size_t)b * Ss + key0 + tid] * (-1e9f);
    __syncthreads();

    // S = Q K^T : 4 key-subtiles x 2 k-chunks
    f32x4 sa[4];
#pragma unroll
    for (int i = 0; i < 4; ++i) sa[i] = zero;
#pragma unroll
    for (int kk = 0; kk < 2; ++kk) {
#pragma unroll
      for (int sub = 0; sub < 4; ++sub) {
        bf16x8 kf = *(const bf16x8*)(&Ks[(sub * 16 + lr) * 64 + kk * 32 + g * 8]);
        sa[sub] = mfma16(qf[kk], kf, sa[sub]);
      }
    }
    // logits: lane holds rows g*4+r (r=0..3), key cols sub*16+lr
    float lg[4][4];
#pragma unroll
    for (int sub = 0; sub < 4; ++sub) {
      const float mk = ms[sub * 16 + lr];
#pragma unroll
      for (int r = 0; r < 4; ++r) lg[sub][r] = sa[sub][r] * 0.125f + mk;
    }
    // online softmax (row reductions across the 16-lane group)
#pragma unroll
    for (int r = 0; r < 4; ++r) {
      float rm = fmaxf(fmaxf(lg[0][r], lg[1][r]), fmaxf(lg[2][r], lg[3][r]));
#pragma unroll
      for (int ofs = 1; ofs < 16; ofs <<= 1) rm = fmaxf(rm, __shfl_xor(rm, ofs));
      const float mnew = fmaxf(mrun[r], rm);
      const float corr = __expf(mrun[r] - mnew);
      float ps = 0.f;
#pragma unroll
      for (int sub = 0; sub < 4; ++sub) {
        float p = __expf(lg[sub][r] - mnew);
        lg[sub][r] = p;
        ps += p;
      }
#pragma unroll
      for (int ofs = 1; ofs < 16; ofs <<= 1) ps += __shfl_xor(ps, ofs);
      lrun[r] = lrun[r] * corr + ps;
      mrun[r] = mnew;
#pragma unroll
      for (int dsub = 0; dsub < 4; ++dsub) o[dsub][r] *= corr;
    }
    // P -> LDS (bf16) to re-layout for the PV A-operand
#pragma unroll
    for (int sub = 0; sub < 4; ++sub)
#pragma unroll
      for (int r = 0; r < 4; ++r)
        Ps[wid][(g * 4 + r) * 64 + sub * 16 + lr] = f2bf(lg[sub][r]);
    __syncthreads();
    // O += P V : A rows = lr, k = keys; B cols = dep (from Vt)
#pragma unroll
    for (int kc = 0; kc < 2; ++kc) {
      bf16x8 pf = *(const bf16x8*)(&Ps[wid][lr * 64 + kc * 32 + g * 8]);
#pragma unroll
      for (int dsub = 0; dsub < 4; ++dsub) {
        bf16x8 vf = *(const bf16x8*)(&Vt[(dsub * 16 + lr) * 64 + kc * 32 + g * 8]);
        o[dsub] = mfma16(pf, vf, o[dsub]);
      }
    }
    __syncthreads();
  }
  // normalize + store bf16
#pragma unroll
  for (int dsub = 0; dsub < 4; ++dsub) {
    const int col = h * 64 + dsub * 16 + lr;
#pragma unroll
    for (int r = 0; r < 4; ++r) {
      const int row = q0 + wid * 16 + g * 4 + r;
      const float val = o[dsub][r] / lrun[r];
      Op[((size_t)b * Ss + row) * Dd + col] = f2bf(val);
    }
  }
}

}  // namespace

extern "C" void kernel_launch(void* const* d_in, const int* in_sizes, int n_in,
                              void* d_out, int out_size, void* d_ws, size_t ws_size,
                              hipStream_t stream) {
  (void)in_sizes; (void)n_in; (void)out_size; (void)ws_size;
  const float* v = (const float*)d_in[0];
  const float* q = (const float*)d_in[1];
  const float* k = (const float*)d_in[2];
  const float* mask = (const float*)d_in[3];
  const float* Wq = (const float*)d_in[4];
  const float* bq = (const float*)d_in[5];
  const float* Wv = (const float*)d_in[6];
  const float* bv = (const float*)d_in[7];
  const float* Wo = (const float*)d_in[8];
  const float* bo = (const float*)d_in[9];
  float* out = (float*)d_out;

  u16* ws = (u16*)d_ws;
  u16* WqT = ws;                           // 1M u16
  u16* WvT = WqT + 1024 * 1024;            // 1M
  u16* WoT = WvT + 1024 * 1024;            // 1M
  u16* Qp = WoT + 1024 * 1024;             // 4M each below
  u16* Kp = Qp + 4096 * 1024;
  u16* Vp = Kp + 4096 * 1024;
  u16* AO = Vp + 4096 * 1024;              // total 19M u16 = 38 MB

  wt_transpose<<<dim3(32, 32, 3), 256, 0, stream>>>(Wq, Wv, Wo, ws);
  // NOTE: reference projects K with the QUERY weights (wQuery(k)).
  gemm_bt<true, false><<<dim3(8, 32), 256, 0, stream>>>(q, WqT, bq, Qp, 4096, 1024, 1024);
  gemm_bt<true, false><<<dim3(8, 32), 256, 0, stream>>>(k, WqT, bq, Kp, 4096, 1024, 1024);
  gemm_bt<true, false><<<dim3(8, 32), 256, 0, stream>>>(v, WvT, bv, Vp, 4096, 1024, 1024);
  attn<<<dim3(Ss / 64, 2 * Hh), 256, 0, stream>>>(Qp, Kp, Vp, mask, AO);
  gemm_bt<false, true><<<dim3(8, 32), 256, 0, stream>>>(AO, WoT, bo, out, 4096, 1024, 1024);
}

// Round 2
// 253.139 us; speedup vs baseline: 1.3791x; 1.3791x over previous
//
#include <hip/hip_runtime.h>
#include <cstddef>

// MultiHeadAttentionLayer: B=2, S=2048, D=1024, H=16, DEPTH=64
// R1: XOR chunk-swizzle (chunk ^= row&7 within 128B rows) on ALL LDS tiles
//     (Ks/Vt/Ps/As/Bs) to kill the 16-way ds_read_b128 bank conflicts
//     (SQ_LDS_BANK_CONFLICT was 6.2e7 on attn). global_load_lds tiles keep a
//     linear dest and pre-swizzle the SOURCE address (involution, rule #21).
//     V is pre-transposed by the V-projection GEMM epilogue so attn stages
//     V^T via global_load_lds (no in-kernel scalar transpose).

namespace {

constexpr int Ss = 2048;
constexpr int Dd = 1024;
constexpr int Hh = 16;
constexpr int Mm = 4096;  // B*S

typedef unsigned short u16;
typedef __attribute__((ext_vector_type(8))) __bf16 bf16x8;
typedef __attribute__((ext_vector_type(4))) float f32x4;

__device__ __forceinline__ u16 f2bf(float f) {
  unsigned int u = __float_as_uint(f);
  return (u16)((u + 0x7fffu + ((u >> 16) & 1u)) >> 16);  // RNE
}

__device__ __forceinline__ void gload_lds16(const void* g, void* l) {
  __builtin_amdgcn_global_load_lds(
      (__attribute__((address_space(1))) void*)g,
      (__attribute__((address_space(3))) void*)l, 16, 0, 0);
}

__device__ __forceinline__ f32x4 mfma16(bf16x8 a, bf16x8 b, f32x4 c) {
  return __builtin_amdgcn_mfma_f32_16x16x32_bf16(a, b, c, 0, 0, 0);
}

// swizzled u16 index within a [rows][64 u16] LDS tile (128B rows, 16B chunks)
__device__ __forceinline__ int swz(int row, int col) {
  return row * 64 + ((((col >> 3) ^ (row & 7)) << 3) | (col & 7));
}
// pre-swizzled source column chunk for global_load_lds staging of 8 rows:
// lane l writes LDS (row=rb+(l>>3), chunk=l&7); source chunk = (l&7)^(l>>3).
__device__ __forceinline__ int src_col(int lane) {
  return ((lane & 7) ^ (lane >> 3)) * 8;
}

// ---------------------------------------------------------------- transpose
// W (f32, K-major 1024x1024) -> WT (bf16, N-major 1024x1024), 3 weights via z.
__global__ __launch_bounds__(256) void wt_transpose(const float* __restrict__ W0,
                                                    const float* __restrict__ W1,
                                                    const float* __restrict__ W2,
                                                    u16* __restrict__ wsbase) {
  const float* W = (blockIdx.z == 0) ? W0 : (blockIdx.z == 1) ? W1 : W2;
  u16* WT = wsbase + (size_t)blockIdx.z * (1024 * 1024);
  __shared__ float tile[32][33];
  const int tx = threadIdx.x & 31;
  const int ty = threadIdx.x >> 5;  // 0..7
  const int n0 = blockIdx.x * 32;
  const int k0 = blockIdx.y * 32;
#pragma unroll
  for (int i = 0; i < 4; ++i)
    tile[ty + i * 8][tx] = W[(size_t)(k0 + ty + i * 8) * 1024 + n0 + tx];
  __syncthreads();
#pragma unroll
  for (int i = 0; i < 4; ++i)
    WT[(size_t)(n0 + ty + i * 8) * 1024 + k0 + tx] = f2bf(tile[tx][ty + i * 8]);
}

// ---------------------------------------------------------------- GEMM (B^T)
// C[M,N] = A[M,K] @ BT[N,K]^T + bias[N].  128x128 tile, BK=64, 4 waves.
// A_F32: A is f32, reg-staged+converted; else bf16 via global_load_lds.
// C_F32: C stored f32 (d_out); else bf16 (ws).
// C_TRANS: store C^T (bf16) with row stride M (for V: per-head V^T rows).
template <bool A_F32, bool C_F32, bool C_TRANS = false>
__global__ __launch_bounds__(256) void gemm_bt(const void* __restrict__ Ap,
                                               const u16* __restrict__ Bt,
                                               const float* __restrict__ bias,
                                               void* __restrict__ Cp,
                                               int M, int N, int K) {
  __shared__ u16 As[128 * 64];
  __shared__ u16 Bs[128 * 64];
  const int tid = threadIdx.x;
  const int wid = tid >> 6;
  const int lane = tid & 63;
  const int g = lane >> 4;
  const int lr = lane & 15;
  const int n0 = blockIdx.x * 128;
  const int m0 = blockIdx.y * 128;
  const int wr = wid >> 1, wc = wid & 1;  // wave -> 64x64 quadrant

  const f32x4 zero = {0.f, 0.f, 0.f, 0.f};
  f32x4 acc[4][4];
#pragma unroll
  for (int m = 0; m < 4; ++m)
#pragma unroll
    for (int n = 0; n < 4; ++n) acc[m][n] = zero;

  for (int k0 = 0; k0 < K; k0 += 64) {
    if constexpr (A_F32) {
      const float* A = (const float*)Ap;
#pragma unroll
      for (int i = 0; i < 8; ++i) {
        int e = i * 256 + tid;          // 2048 float4-chunks of the 128x64 tile
        int row = e >> 4;
        int c4 = (e & 15) << 2;
        const float4 v = *(const float4*)(&A[(size_t)(m0 + row) * K + k0 + c4]);
        ushort4 o4 = make_ushort4(f2bf(v.x), f2bf(v.y), f2bf(v.z), f2bf(v.w));
        *(ushort4*)(&As[swz(row, c4)]) = o4;
      }
    } else {
      const u16* A = (const u16*)Ap;
#pragma unroll
      for (int j = 0; j < 4; ++j) {
        int rb = (wid * 4 + j) * 8;  // 8 rows per instruction
        gload_lds16(&A[(size_t)(m0 + rb + (lane >> 3)) * K + k0 + src_col(lane)],
                    &As[rb * 64]);
      }
    }
#pragma unroll
    for (int j = 0; j < 4; ++j) {
      int rb = (wid * 4 + j) * 8;
      gload_lds16(&Bt[(size_t)(n0 + rb + (lane >> 3)) * K + k0 + src_col(lane)],
                  &Bs[rb * 64]);
    }
    __syncthreads();
#pragma unroll
    for (int kk = 0; kk < 2; ++kk) {
      bf16x8 a[4], b[4];
#pragma unroll
      for (int m = 0; m < 4; ++m)
        a[m] = *(const bf16x8*)(&As[swz(wr * 64 + m * 16 + lr, kk * 32 + g * 8)]);
#pragma unroll
      for (int n = 0; n < 4; ++n)
        b[n] = *(const bf16x8*)(&Bs[swz(wc * 64 + n * 16 + lr, kk * 32 + g * 8)]);
#pragma unroll
      for (int m = 0; m < 4; ++m)
#pragma unroll
        for (int n = 0; n < 4; ++n) acc[m][n] = mfma16(a[m], b[n], acc[m][n]);
    }
    __syncthreads();
  }
  // epilogue: C/D layout col=lane&15, row=(lane>>4)*4+reg  [m89-verified]
#pragma unroll
  for (int n = 0; n < 4; ++n) {
    const int col = n0 + wc * 64 + n * 16 + lr;
    const float bv = bias[col];
#pragma unroll
    for (int m = 0; m < 4; ++m) {
      const int rowb = m0 + wr * 64 + m * 16 + g * 4;
      if constexpr (C_TRANS) {
        ushort4 o4 = make_ushort4(f2bf(acc[m][n][0] + bv), f2bf(acc[m][n][1] + bv),
                                  f2bf(acc[m][n][2] + bv), f2bf(acc[m][n][3] + bv));
        *(ushort4*)(&((u16*)Cp)[(size_t)col * M + rowb]) = o4;
      } else {
#pragma unroll
        for (int r = 0; r < 4; ++r) {
          float val = acc[m][n][r] + bv;
          if constexpr (C_F32)
            ((float*)Cp)[(size_t)(rowb + r) * N + col] = val;
          else
            ((u16*)Cp)[(size_t)(rowb + r) * N + col] = f2bf(val);
        }
      }
    }
  }
}

// ---------------------------------------------------------------- attention
// grid: (S/64, B*H). Block = 4 waves; wave w owns q-rows [q0+16w, q0+16w+16).
// KV tiles of 64 keys; K and V^T staged via global_load_lds (pre-swizzled src).
// VpT layout: [D=1024][M=4096] u16 (element (token m, dim d) at d*M + m).
__global__ __launch_bounds__(256) void attn(const u16* __restrict__ Qp,
                                            const u16* __restrict__ Kp,
                                            const u16* __restrict__ VpT,
                                            const float* __restrict__ mask,
                                            u16* __restrict__ Op) {
  __shared__ u16 Ks[64 * 64];      // Ks[key][d]   (swizzled)
  __shared__ u16 Vt[64 * 64];      // Vt[d][key]   (swizzled)
  __shared__ u16 Ps[4][16 * 64];   // per-wave P tile [row][key] (swizzled)
  __shared__ float ms[64];         // mask * -1e9 for this key tile
  const int tid = threadIdx.x;
  const int wid = tid >> 6;
  const int lane = tid & 63;
  const int g = lane >> 4;
  const int lr = lane & 15;
  const int q0 = blockIdx.x * 64;
  const int bh = blockIdx.y;
  const int b = bh >> 4;
  const int h = bh & 15;
  const size_t base = ((size_t)b * Ss) * Dd + (size_t)h * 64;
  const size_t vbase = (size_t)h * 64 * Mm + (size_t)b * Ss;

  // Q fragments (A operand): lane row = lr, k = kk*32 + g*8 .. +8
  bf16x8 qf[2];
  {
    const int row = q0 + wid * 16 + lr;
#pragma unroll
    for (int kk = 0; kk < 2; ++kk)
      qf[kk] = *(const bf16x8*)(&Qp[base + (size_t)row * Dd + kk * 32 + g * 8]);
  }

  const f32x4 zero = {0.f, 0.f, 0.f, 0.f};
  f32x4 o[4];
#pragma unroll
  for (int i = 0; i < 4; ++i) o[i] = zero;
  float mrun[4], lrun[4];
#pragma unroll
  for (int r = 0; r < 4; ++r) {
    mrun[r] = -1e30f;
    lrun[r] = 0.f;
  }

  for (int t = 0; t < Ss / 64; ++t) {
    const int key0 = t * 64;
    // stage K tile [64 keys][64 d] (swizzled via source)
#pragma unroll
    for (int j = 0; j < 2; ++j) {
      int rb = (wid * 2 + j) * 8;
      gload_lds16(&Kp[base + (size_t)(key0 + rb + (lane >> 3)) * Dd + src_col(lane)],
                  &Ks[rb * 64]);
    }
    // stage V^T tile [64 d][64 keys] from VpT (swizzled via source)
#pragma unroll
    for (int j = 0; j < 2; ++j) {
      int rb = (wid * 2 + j) * 8;
      gload_lds16(&VpT[vbase + (size_t)(rb + (lane >> 3)) * Mm + key0 + src_col(lane)],
                  &Vt[rb * 64]);
    }
    if (tid < 64) ms[tid] = mask[(size_t)b * Ss + key0 + tid] * (-1e9f);
    __syncthreads();

    // S = Q K^T : 4 key-subtiles x 2 k-chunks
    f32x4 sa[4];
#pragma unroll
    for (int i = 0; i < 4; ++i) sa[i] = zero;
#pragma unroll
    for (int kk = 0; kk < 2; ++kk) {
#pragma unroll
      for (int sub = 0; sub < 4; ++sub) {
        bf16x8 kf = *(const bf16x8*)(&Ks[swz(sub * 16 + lr, kk * 32 + g * 8)]);
        sa[sub] = mfma16(qf[kk], kf, sa[sub]);
      }
    }
    // logits: lane holds rows g*4+r (r=0..3), key cols sub*16+lr
    float lg[4][4];
#pragma unroll
    for (int sub = 0; sub < 4; ++sub) {
      const float mk = ms[sub * 16 + lr];
#pragma unroll
      for (int r = 0; r < 4; ++r) lg[sub][r] = sa[sub][r] * 0.125f + mk;
    }
    // online softmax (row reductions across the 16-lane group)
#pragma unroll
    for (int r = 0; r < 4; ++r) {
      float rm = fmaxf(fmaxf(lg[0][r], lg[1][r]), fmaxf(lg[2][r], lg[3][r]));
#pragma unroll
      for (int ofs = 1; ofs < 16; ofs <<= 1) rm = fmaxf(rm, __shfl_xor(rm, ofs));
      const float mnew = fmaxf(mrun[r], rm);
      const float corr = __expf(mrun[r] - mnew);
      float ps = 0.f;
#pragma unroll
      for (int sub = 0; sub < 4; ++sub) {
        float p = __expf(lg[sub][r] - mnew);
        lg[sub][r] = p;
        ps += p;
      }
#pragma unroll
      for (int ofs = 1; ofs < 16; ofs <<= 1) ps += __shfl_xor(ps, ofs);
      lrun[r] = lrun[r] * corr + ps;
      mrun[r] = mnew;
#pragma unroll
      for (int dsub = 0; dsub < 4; ++dsub) o[dsub][r] *= corr;
    }
    // P -> LDS (bf16, swizzled); Ps is per-wave so no barrier needed before PV
#pragma unroll
    for (int sub = 0; sub < 4; ++sub)
#pragma unroll
      for (int r = 0; r < 4; ++r)
        Ps[wid][swz(g * 4 + r, sub * 16 + lr)] = f2bf(lg[sub][r]);
    // O += P V : A rows = lr (q-row), k = keys; B cols = d (from Vt)
#pragma unroll
    for (int kc = 0; kc < 2; ++kc) {
      bf16x8 pf = *(const bf16x8*)(&Ps[wid][swz(lr, kc * 32 + g * 8)]);
#pragma unroll
      for (int dsub = 0; dsub < 4; ++dsub) {
        bf16x8 vf = *(const bf16x8*)(&Vt[swz(dsub * 16 + lr, kc * 32 + g * 8)]);
        o[dsub] = mfma16(pf, vf, o[dsub]);
      }
    }
    __syncthreads();
  }
  // normalize + store bf16
#pragma unroll
  for (int dsub = 0; dsub < 4; ++dsub) {
    const int col = h * 64 + dsub * 16 + lr;
#pragma unroll
    for (int r = 0; r < 4; ++r) {
      const int row = q0 + wid * 16 + g * 4 + r;
      const float val = o[dsub][r] / lrun[r];
      Op[((size_t)b * Ss + row) * Dd + col] = f2bf(val);
    }
  }
}

}  // namespace

extern "C" void kernel_launch(void* const* d_in, const int* in_sizes, int n_in,
                              void* d_out, int out_size, void* d_ws, size_t ws_size,
                              hipStream_t stream) {
  (void)in_sizes; (void)n_in; (void)out_size; (void)ws_size;
  const float* v = (const float*)d_in[0];
  const float* q = (const float*)d_in[1];
  const float* k = (const float*)d_in[2];
  const float* mask = (const float*)d_in[3];
  const float* Wq = (const float*)d_in[4];
  const float* bq = (const float*)d_in[5];
  const float* Wv = (const float*)d_in[6];
  const float* bv = (const float*)d_in[7];
  const float* Wo = (const float*)d_in[8];
  const float* bo = (const float*)d_in[9];
  float* out = (float*)d_out;

  u16* ws = (u16*)d_ws;
  u16* WqT = ws;                           // 1M u16
  u16* WvT = WqT + 1024 * 1024;            // 1M
  u16* WoT = WvT + 1024 * 1024;            // 1M
  u16* Qp = WoT + 1024 * 1024;             // 4M each below
  u16* Kp = Qp + 4096 * 1024;
  u16* VpT = Kp + 4096 * 1024;             // V^T: [1024][4096]
  u16* AO = VpT + 4096 * 1024;             // total 19M u16 = 38 MB

  wt_transpose<<<dim3(32, 32, 3), 256, 0, stream>>>(Wq, Wv, Wo, ws);
  // NOTE: reference projects K with the QUERY weights (wQuery(k)).
  gemm_bt<true, false><<<dim3(8, 32), 256, 0, stream>>>(q, WqT, bq, Qp, 4096, 1024, 1024);
  gemm_bt<true, false><<<dim3(8, 32), 256, 0, stream>>>(k, WqT, bq, Kp, 4096, 1024, 1024);
  gemm_bt<true, false, true><<<dim3(8, 32), 256, 0, stream>>>(v, WvT, bv, VpT, 4096, 1024, 1024);
  attn<<<dim3(Ss / 64, 2 * Hh), 256, 0, stream>>>(Qp, Kp, VpT, mask, AO);
  gemm_bt<false, true><<<dim3(8, 32), 256, 0, stream>>>(AO, WoT, bo, out, 4096, 1024, 1024);
}